// Round 14
// baseline (67.853 us; speedup 1.0000x reference)
//
#include <hip/hip_runtime.h>

#define TS 64
#define HD 16
#define SEGLEN 16
#define RAY_EXT 10.0f

typedef float    v4f __attribute__((ext_vector_type(4)));
typedef _Float16 v8h __attribute__((ext_vector_type(8)));
typedef unsigned v4u __attribute__((ext_vector_type(4)));

__device__ __forceinline__ float fast_exp2(float x) { return __builtin_amdgcn_exp2f(x); }
__device__ __forceinline__ float fast_log2(float x) { return __builtin_amdgcn_logf(x); }

// f32 pair -> packed f16x2 (v_cvt_pkrtz_f16_f32) -- builtin only, NO inline asm.
// (Inline asm in the MFMA dataflow caused schedule-dependent corruption:
//  R5/R6/R12 NaN. All-builtin variants R9/R11/R13 are clean.)
__device__ __forceinline__ unsigned pack_f16x2(float a, float b) {
    return __builtin_bit_cast(unsigned, __builtin_amdgcn_cvt_pkrtz(a, b));
}

// fragment with k-slots 0..3 live, 4..7 zero (u32-level construction: fast path)
__device__ __forceinline__ v8h make_frag(unsigned lo, unsigned hi) {
    return __builtin_bit_cast(v8h, (v4u){lo, hi, 0u, 0u});
}

__device__ __forceinline__ v4f mfma32(v8h a, v8h b, v4f c) {
    return __builtin_amdgcn_mfma_f32_16x16x32_f16(a, b, c, 0, 0, 0);
}

__global__ __launch_bounds__(256) void radiance_kernel(
    const float* __restrict__ rays_o,
    const float* __restrict__ rays_d,
    const float* __restrict__ u,      // (T, N)
    const float* __restrict__ aabb,   // (2,3)
    const float* __restrict__ W1,     // (3,16)
    const float* __restrict__ b1,     // (16)
    const float* __restrict__ Wsigma, // (16,1)
    const float* __restrict__ Wcolor, // (16,3)
    const float* __restrict__ Wdir,   // (3,3)
    float* __restrict__ out,          // (N,5)
    int N)
{
    const float LOG2E = 1.44269504088896340736f;
    const float eps = 1e-9f;

    int tid  = blockIdx.x * blockDim.x + threadIdx.x;
    int lane = threadIdx.x & 63;
    int s    = lane & 15;     // ray-within-wave == MFMA column
    int grp  = lane >> 4;     // segment 0..3     == MFMA k/row block
    int wave = tid >> 6;
    int ray  = wave * 16 + s;

    float ox = rays_o[ray * 3 + 0];
    float oy = rays_o[ray * 3 + 1];
    float oz = rays_o[ray * 3 + 2];
    float dx = rays_d[ray * 3 + 0];
    float dy = rays_d[ray * 3 + 1];
    float dz = rays_d[ray * 3 + 2];

    float a0x = aabb[0], a0y = aabb[1], a0z = aabb[2];
    float a1x = aabb[3], a1y = aabb[4], a1z = aabb[5];

    // slab test (no early return: MFMA needs full waves)
    float dsx = (fabsf(dx) < eps) ? eps : dx;
    float dsy = (fabsf(dy) < eps) ? eps : dy;
    float dsz = (fabsf(dz) < eps) ? eps : dz;
    float t1x = (a0x - ox) / dsx, t2x = (a1x - ox) / dsx;
    float t1y = (a0y - oy) / dsy, t2y = (a1y - oy) / dsy;
    float t1z = (a0z - oz) / dsz, t2z = (a1z - oz) / dsz;
    float tnear = fmaxf(fmaxf(fminf(t1x, t2x), fmaxf(fminf(t1y, t2y), fminf(t1z, t2z))), 0.0f);
    float tfar  = fminf(fmaxf(t1x, t2x), fminf(fmaxf(t1y, t2y), fmaxf(t1z, t2z)));
    bool active = tnear < tfar;
    // sanitize inactive rays: pipeline stays finite, all weights w == 0.
    if (!active) { tnear = 0.0f; tfar = 0.0f; }

    // ---- A1 values: A1[m=s][slot i] = {W1[0][s],W1[1][s],W1[2][s],b1[s]}
    unsigned w1lo = pack_f16x2(W1[0 * HD + s], W1[1 * HD + s]);
    unsigned w1hi = pack_f16x2(W1[2 * HD + s], b1[s]);

    // ---- A2 values: row m = s -> output o = s&3, owner pass = s>>2.
    //      A2[m=s][slot i] = W2eff[o][4*grp + i], pre-scaled into exp2 domain.
    int oidx = s & 3;
    int rgrp = s >> 2;
    float w2v0, w2v1, w2v2, w2v3;
    {
        int k0 = 4 * grp;
        if (oidx == 0) {
            w2v0 = LOG2E * Wsigma[k0 + 0]; w2v1 = LOG2E * Wsigma[k0 + 1];
            w2v2 = LOG2E * Wsigma[k0 + 2]; w2v3 = LOG2E * Wsigma[k0 + 3];
        } else {
            int c = oidx - 1;
            w2v0 = -LOG2E * Wcolor[(k0 + 0) * 3 + c];
            w2v1 = -LOG2E * Wcolor[(k0 + 1) * 3 + c];
            w2v2 = -LOG2E * Wcolor[(k0 + 2) * 3 + c];
            w2v3 = -LOG2E * Wcolor[(k0 + 3) * 3 + c];
        }
    }
    unsigned a2lo = pack_f16x2(w2v0, w2v1);
    unsigned a2hi = pack_f16x2(w2v2, w2v3);

    // ---- masked fragment halves as plain u32 (VGPR diet vs pre-built v8h arrays;
    //      make_frag at use lets the compiler share the zero registers)
    unsigned a1lo0 = grp == 0 ? w1lo : 0u, a1hi0 = grp == 0 ? w1hi : 0u;
    unsigned a1lo1 = grp == 1 ? w1lo : 0u, a1hi1 = grp == 1 ? w1hi : 0u;
    unsigned a1lo2 = grp == 2 ? w1lo : 0u, a1hi2 = grp == 2 ? w1hi : 0u;
    unsigned a1lo3 = grp == 3 ? w1lo : 0u, a1hi3 = grp == 3 ? w1hi : 0u;
    unsigned a2lo0 = rgrp == 0 ? a2lo : 0u, a2hi0 = rgrp == 0 ? a2hi : 0u;
    unsigned a2lo1 = rgrp == 1 ? a2lo : 0u, a2hi1 = rgrp == 1 ? a2hi : 0u;
    unsigned a2lo2 = rgrp == 2 ? a2lo : 0u, a2hi2 = rgrp == 2 ? a2hi : 0u;
    unsigned a2lo3 = rgrp == 3 ? a2lo : 0u, a2hi3 = rgrp == 3 ? a2hi : 0u;
    const v4f zero4 = {0.f, 0.f, 0.f, 0.f};

    // direction encoding (pre-scaled by -log2e), per-ray
    float dn = sqrtf(dx * dx + dy * dy + dz * dz);
    float inv_dn = 1.0f / dn;
    float ux = dx * inv_dn, uy = dy * inv_dn, uz = dz * inv_dn;
    float dd0 = -LOG2E * (ux * Wdir[0] + uy * Wdir[3] + uz * Wdir[6]);
    float dd1 = -LOG2E * (ux * Wdir[1] + uy * Wdir[4] + uz * Wdir[7]);
    float dd2 = -LOG2E * (ux * Wdir[2] + uy * Wdir[5] + uz * Wdir[8]);

    const float invT = 1.0f / (float)TS;
    float rngT = (tfar - tnear) * invT;
    float tfinal = tfar * RAY_EXT;

    const int t0 = grp * SEGLEN;
    float t0f = (float)t0;

    // rolling u prefetch (2 ahead)
    float u_cur = u[(size_t)t0 * N + ray];
    float u_nxt = u[(size_t)(t0 + 1) * N + ray];

    float cm0 = 0.f, cm1 = 0.f, cm2 = 0.f, am = 0.f, dm = 0.f;
    float Tr = 1.0f;
    float ts = fmaf(rngT, t0f + u_cur, tnear);

#pragma unroll
    for (int t = 0; t < SEGLEN; ++t) {
        int gp = t0 + t + 2; gp = gp < TS - 1 ? gp : TS - 1;
        float u_fut = u[(size_t)gp * N + ray];        // used NEXT iteration

        float tf1 = t0f + (float)(t + 1);
        float tsn = fmaf(rngT, tf1 + u_nxt, tnear);
        // t == SEGLEN-1 is compile-time under full unroll; grp==3 select is per-lane
        float delta;
        if (t == SEGLEN - 1)
            delta = ((grp == 3) ? tfinal : tsn) - ts;
        else
            delta = tsn - ts;

        float x = fmaf(ts, dx, ox);
        float y = fmaf(ts, dy, oy);
        float z = fmaf(ts, dz, oz);
        v8h bin = make_frag(pack_f16x2(x, y), pack_f16x2(z, 1.0f));

        // ---- layer 1: 4 independent MFMAs (only mutual dep: bin)
        v4f d1_0 = mfma32(make_frag(a1lo0, a1hi0), bin, zero4);
        v4f d1_1 = mfma32(make_frag(a1lo1, a1hi1), bin, zero4);
        v4f d1_2 = mfma32(make_frag(a1lo2, a1hi2), bin, zero4);
        v4f d1_3 = mfma32(make_frag(a1lo3, a1hi3), bin, zero4);

        // ---- relu in f32, then builtin pack
        v8h h0 = make_frag(pack_f16x2(fmaxf(d1_0[0], 0.f), fmaxf(d1_0[1], 0.f)),
                           pack_f16x2(fmaxf(d1_0[2], 0.f), fmaxf(d1_0[3], 0.f)));
        v8h h1 = make_frag(pack_f16x2(fmaxf(d1_1[0], 0.f), fmaxf(d1_1[1], 0.f)),
                           pack_f16x2(fmaxf(d1_1[2], 0.f), fmaxf(d1_1[3], 0.f)));
        v8h h2 = make_frag(pack_f16x2(fmaxf(d1_2[0], 0.f), fmaxf(d1_2[1], 0.f)),
                           pack_f16x2(fmaxf(d1_2[2], 0.f), fmaxf(d1_2[3], 0.f)));
        v8h h3 = make_frag(pack_f16x2(fmaxf(d1_3[0], 0.f), fmaxf(d1_3[1], 0.f)),
                           pack_f16x2(fmaxf(d1_3[2], 0.f), fmaxf(d1_3[3], 0.f)));

        // ---- layer 2: two independent 2-deep chains (halved critical path),
        //      combined with one vector add. A/B vs R13: isolates reassoc error.
        v4f accA = mfma32(make_frag(a2lo1, a2hi1), h1,
                   mfma32(make_frag(a2lo0, a2hi0), h0, zero4));
        v4f accB = mfma32(make_frag(a2lo3, a2hi3), h3,
                   mfma32(make_frag(a2lo2, a2hi2), h2, zero4));
        v4f acc = accA + accB;

        // acc[0] = sigma-logit*log2e ; acc[1..3] = -color-logit*log2e (sans dir term)
        float sp = acc[0];
        float c0 = acc[1] + dd0;
        float c1 = acc[2] + dd1;
        float c2 = acc[3] + dd2;

        float F = fmaxf(sp, 0.0f) + fast_log2(1.0f + fast_exp2(-fabsf(sp)));
        float e = fast_exp2(-F * (delta * dn));

        float col0 = __builtin_amdgcn_rcpf(1.0f + fast_exp2(c0));
        float col1 = __builtin_amdgcn_rcpf(1.0f + fast_exp2(c1));
        float col2 = __builtin_amdgcn_rcpf(1.0f + fast_exp2(c2));

        float Trn = Tr * e;
        float w = Tr - Trn;       // == (1-e)*Tr
        Tr = Trn;

        cm0 = fmaf(w, col0, cm0);
        cm1 = fmaf(w, col1, cm1);
        cm2 = fmaf(w, col2, cm2);
        am += w;
        dm = fmaf(w, ts, dm);

        ts = tsn;
        u_nxt = u_fut;
    }

    // ---- combine 4 segments across lane groups: butterfly xor 16, then 32.
#pragma unroll
    for (int x = 16; x <= 32; x <<= 1) {
        float pcm0 = __shfl_xor(cm0, x, 64);
        float pcm1 = __shfl_xor(cm1, x, 64);
        float pcm2 = __shfl_xor(cm2, x, 64);
        float pam  = __shfl_xor(am, x, 64);
        float pdm  = __shfl_xor(dm, x, 64);
        float pTr  = __shfl_xor(Tr, x, 64);
        cm0 = fmaf(Tr, pcm0, cm0);
        cm1 = fmaf(Tr, pcm1, cm1);
        cm2 = fmaf(Tr, pcm2, cm2);
        am  = fmaf(Tr, pam,  am);
        dm  = fmaf(Tr, pdm,  dm);
        Tr *= pTr;
    }

    if (grp == 0) {
        float* o5 = out + (size_t)ray * 5;
        o5[0] = active ? cm0 : 0.0f;
        o5[1] = active ? cm1 : 0.0f;
        o5[2] = active ? cm2 : 0.0f;
        o5[3] = active ? am  : 0.0f;
        o5[4] = active ? dm  : 0.0f;
    }
}

extern "C" void kernel_launch(void* const* d_in, const int* in_sizes, int n_in,
                              void* d_out, int out_size, void* d_ws, size_t ws_size,
                              hipStream_t stream) {
    const float* rays_o = (const float*)d_in[0];
    const float* rays_d = (const float*)d_in[1];
    const float* u      = (const float*)d_in[2];
    const float* aabb   = (const float*)d_in[3];
    const float* W1     = (const float*)d_in[4];
    const float* b1     = (const float*)d_in[5];
    const float* Wsigma = (const float*)d_in[6];
    const float* Wcolor = (const float*)d_in[7];
    const float* Wdir   = (const float*)d_in[8];
    float* out = (float*)d_out;

    int N = in_sizes[0] / 3;
    long long threads = (long long)N * 4;   // 4 lanes (segments) per ray
    int blocks = (int)((threads + 255) / 256);
    radiance_kernel<<<blocks, 256, 0, stream>>>(rays_o, rays_d, u, aabb,
                                                W1, b1, Wsigma, Wcolor, Wdir,
                                                out, N);
}

// Round 15
// 65.997 us; speedup vs baseline: 1.0281x; 1.0281x over previous
//
#include <hip/hip_runtime.h>

#define TS 64
#define HD 16
#define SEGLEN 16
#define RAY_EXT 10.0f

typedef float    v4f __attribute__((ext_vector_type(4)));
typedef _Float16 v8h __attribute__((ext_vector_type(8)));
typedef unsigned v4u __attribute__((ext_vector_type(4)));

__device__ __forceinline__ float fast_exp2(float x) { return __builtin_amdgcn_exp2f(x); }
__device__ __forceinline__ float fast_log2(float x) { return __builtin_amdgcn_logf(x); }

// f32 pair -> packed f16x2 (v_cvt_pkrtz_f16_f32) -- builtin only, NO inline asm
// (asm in MFMA dataflow = schedule-dependent corruption: R5/R6/R12 NaN, R10 0.25)
__device__ __forceinline__ unsigned pack_f16x2(float a, float b) {
    return __builtin_bit_cast(unsigned, __builtin_amdgcn_cvt_pkrtz(a, b));
}

// fragment with k-slots 0..3 live, 4..7 zero
__device__ __forceinline__ v8h make_frag(unsigned lo, unsigned hi) {
    return __builtin_bit_cast(v8h, (v4u){lo, hi, 0u, 0u});
}

__device__ __forceinline__ v4f mfma32(v8h a, v8h b, v4f c) {
    return __builtin_amdgcn_mfma_f32_16x16x32_f16(a, b, c, 0, 0, 0);
}

__global__ __launch_bounds__(256) void radiance_kernel(
    const float* __restrict__ rays_o,
    const float* __restrict__ rays_d,
    const float* __restrict__ u,      // (T, N)
    const float* __restrict__ aabb,   // (2,3)
    const float* __restrict__ W1,     // (3,16)
    const float* __restrict__ b1,     // (16)
    const float* __restrict__ Wsigma, // (16,1)
    const float* __restrict__ Wcolor, // (16,3)
    const float* __restrict__ Wdir,   // (3,3)
    float* __restrict__ out,          // (N,5)
    int N)
{
    const float LOG2E = 1.44269504088896340736f;
    const float eps = 1e-9f;

    int tid  = blockIdx.x * blockDim.x + threadIdx.x;
    int lane = threadIdx.x & 63;
    int s    = lane & 15;     // ray-within-wave == MFMA column
    int grp  = lane >> 4;     // segment 0..3     == MFMA k/row block
    int wave = tid >> 6;
    int ray  = wave * 16 + s;

    float ox = rays_o[ray * 3 + 0];
    float oy = rays_o[ray * 3 + 1];
    float oz = rays_o[ray * 3 + 2];
    float dx = rays_d[ray * 3 + 0];
    float dy = rays_d[ray * 3 + 1];
    float dz = rays_d[ray * 3 + 2];

    float a0x = aabb[0], a0y = aabb[1], a0z = aabb[2];
    float a1x = aabb[3], a1y = aabb[4], a1z = aabb[5];

    // slab test (no early return: MFMA needs full waves)
    float dsx = (fabsf(dx) < eps) ? eps : dx;
    float dsy = (fabsf(dy) < eps) ? eps : dy;
    float dsz = (fabsf(dz) < eps) ? eps : dz;
    float t1x = (a0x - ox) / dsx, t2x = (a1x - ox) / dsx;
    float t1y = (a0y - oy) / dsy, t2y = (a1y - oy) / dsy;
    float t1z = (a0z - oz) / dsz, t2z = (a1z - oz) / dsz;
    float tnear = fmaxf(fmaxf(fminf(t1x, t2x), fmaxf(fminf(t1y, t2y), fminf(t1z, t2z))), 0.0f);
    float tfar  = fminf(fmaxf(t1x, t2x), fminf(fmaxf(t1y, t2y), fmaxf(t1z, t2z)));
    bool active = tnear < tfar;
    // sanitize inactive rays: pipeline stays finite, all weights w == 0.
    if (!active) { tnear = 0.0f; tfar = 0.0f; }

    // ---- A1 values: A1[m=s][slot i] = {W1[0][s],W1[1][s],W1[2][s],b1[s]}
    unsigned w1lo = pack_f16x2(W1[0 * HD + s], W1[1 * HD + s]);
    unsigned w1hi = pack_f16x2(W1[2 * HD + s], b1[s]);

    // ---- A2 values: row m = s -> output o = s&3, owner pass = s>>2.
    //      A2[m=s][slot i] = W2eff[o][4*grp + i], pre-scaled into exp2 domain.
    int oidx = s & 3;
    int rgrp = s >> 2;
    float w2v0, w2v1, w2v2, w2v3;
    {
        int k0 = 4 * grp;
        if (oidx == 0) {
            w2v0 = LOG2E * Wsigma[k0 + 0]; w2v1 = LOG2E * Wsigma[k0 + 1];
            w2v2 = LOG2E * Wsigma[k0 + 2]; w2v3 = LOG2E * Wsigma[k0 + 3];
        } else {
            int c = oidx - 1;
            w2v0 = -LOG2E * Wcolor[(k0 + 0) * 3 + c];
            w2v1 = -LOG2E * Wcolor[(k0 + 1) * 3 + c];
            w2v2 = -LOG2E * Wcolor[(k0 + 2) * 3 + c];
            w2v3 = -LOG2E * Wcolor[(k0 + 3) * 3 + c];
        }
    }
    unsigned a2lo = pack_f16x2(w2v0, w2v1);
    unsigned a2hi = pack_f16x2(w2v2, w2v3);

    // direction encoding (pre-scaled by -log2e), per-ray
    float dn = sqrtf(dx * dx + dy * dy + dz * dz);
    float inv_dn = 1.0f / dn;
    float ux = dx * inv_dn, uy = dy * inv_dn, uz = dz * inv_dn;
    float dd0 = -LOG2E * (ux * Wdir[0] + uy * Wdir[3] + uz * Wdir[6]);
    float dd1 = -LOG2E * (ux * Wdir[1] + uy * Wdir[4] + uz * Wdir[7]);
    float dd2 = -LOG2E * (ux * Wdir[2] + uy * Wdir[5] + uz * Wdir[8]);

    const float invT = 1.0f / (float)TS;
    float rngT = (tfar - tnear) * invT;
    float tfinal = tfar * RAY_EXT;

    const int t0 = grp * SEGLEN;
    float t0f = (float)t0;

    // rolling u prefetch (2 ahead) -- R9 addressing kept verbatim (44-VGPR alloc)
    float u_cur = u[(size_t)t0 * N + ray];
    float u_nxt = u[(size_t)(t0 + 1) * N + ray];

    float cm0 = 0.f, cm1 = 0.f, cm2 = 0.f, am = 0.f, dm = 0.f;
    float Tr = 1.0f;
    float ts = fmaf(rngT, t0f + u_cur, tnear);

#pragma unroll 4
    for (int t = 0; t < SEGLEN; ++t) {
        int gp = t0 + t + 2; gp = gp < TS - 1 ? gp : TS - 1;
        float u_fut = u[(size_t)gp * N + ray];        // used NEXT iteration

        float tf1 = t0f + (float)(t + 1);
        float tsn = fmaf(rngT, tf1 + u_nxt, tnear);
        float tend = (t == SEGLEN - 1) ? ((grp == 3) ? tfinal : tsn) : tsn;
        float delta = tend - ts;

        float x = fmaf(ts, dx, ox);
        float y = fmaf(ts, dy, oy);
        float z = fmaf(ts, dz, oz);
        v8h bin = make_frag(pack_f16x2(x, y), pack_f16x2(z, 1.0f));

        const v4f zero4 = {0.f, 0.f, 0.f, 0.f};

        // ---- passes 0..3: fragments built in-loop (R9's lean-VGPR pattern),
        //      layer-2 as two independent 2-deep chains (halved critical path;
        //      numerically safe per R14: absmax 0.0625)
        v4f accA, accB;
        {
            bool o1 = (grp == 0);
            v4f d1 = mfma32(make_frag(o1 ? w1lo : 0u, o1 ? w1hi : 0u), bin, zero4);
            v8h h = make_frag(pack_f16x2(fmaxf(d1[0], 0.f), fmaxf(d1[1], 0.f)),
                              pack_f16x2(fmaxf(d1[2], 0.f), fmaxf(d1[3], 0.f)));
            bool o2 = (rgrp == 0);
            accA = mfma32(make_frag(o2 ? a2lo : 0u, o2 ? a2hi : 0u), h, zero4);
        }
        {
            bool o1 = (grp == 1);
            v4f d1 = mfma32(make_frag(o1 ? w1lo : 0u, o1 ? w1hi : 0u), bin, zero4);
            v8h h = make_frag(pack_f16x2(fmaxf(d1[0], 0.f), fmaxf(d1[1], 0.f)),
                              pack_f16x2(fmaxf(d1[2], 0.f), fmaxf(d1[3], 0.f)));
            bool o2 = (rgrp == 1);
            accA = mfma32(make_frag(o2 ? a2lo : 0u, o2 ? a2hi : 0u), h, accA);
        }
        {
            bool o1 = (grp == 2);
            v4f d1 = mfma32(make_frag(o1 ? w1lo : 0u, o1 ? w1hi : 0u), bin, zero4);
            v8h h = make_frag(pack_f16x2(fmaxf(d1[0], 0.f), fmaxf(d1[1], 0.f)),
                              pack_f16x2(fmaxf(d1[2], 0.f), fmaxf(d1[3], 0.f)));
            bool o2 = (rgrp == 2);
            accB = mfma32(make_frag(o2 ? a2lo : 0u, o2 ? a2hi : 0u), h, zero4);
        }
        {
            bool o1 = (grp == 3);
            v4f d1 = mfma32(make_frag(o1 ? w1lo : 0u, o1 ? w1hi : 0u), bin, zero4);
            v8h h = make_frag(pack_f16x2(fmaxf(d1[0], 0.f), fmaxf(d1[1], 0.f)),
                              pack_f16x2(fmaxf(d1[2], 0.f), fmaxf(d1[3], 0.f)));
            bool o2 = (rgrp == 3);
            accB = mfma32(make_frag(o2 ? a2lo : 0u, o2 ? a2hi : 0u), h, accB);
        }
        v4f acc = accA + accB;

        // acc[0] = sigma-logit*log2e ; acc[1..3] = -color-logit*log2e (sans dir term)
        float sp = acc[0];
        float c0 = acc[1] + dd0;
        float c1 = acc[2] + dd1;
        float c2 = acc[3] + dd2;

        float F = fmaxf(sp, 0.0f) + fast_log2(1.0f + fast_exp2(-fabsf(sp)));
        float e = fast_exp2(-F * (delta * dn));

        float col0 = __builtin_amdgcn_rcpf(1.0f + fast_exp2(c0));
        float col1 = __builtin_amdgcn_rcpf(1.0f + fast_exp2(c1));
        float col2 = __builtin_amdgcn_rcpf(1.0f + fast_exp2(c2));

        float Trn = Tr * e;
        float w = Tr - Trn;       // == (1-e)*Tr
        Tr = Trn;

        cm0 = fmaf(w, col0, cm0);
        cm1 = fmaf(w, col1, cm1);
        cm2 = fmaf(w, col2, cm2);
        am += w;
        dm = fmaf(w, ts, dm);

        ts = tsn;
        u_nxt = u_fut;
    }

    // ---- combine 4 segments across lane groups: butterfly xor 16, then 32.
#pragma unroll
    for (int x = 16; x <= 32; x <<= 1) {
        float pcm0 = __shfl_xor(cm0, x, 64);
        float pcm1 = __shfl_xor(cm1, x, 64);
        float pcm2 = __shfl_xor(cm2, x, 64);
        float pam  = __shfl_xor(am, x, 64);
        float pdm  = __shfl_xor(dm, x, 64);
        float pTr  = __shfl_xor(Tr, x, 64);
        cm0 = fmaf(Tr, pcm0, cm0);
        cm1 = fmaf(Tr, pcm1, cm1);
        cm2 = fmaf(Tr, pcm2, cm2);
        am  = fmaf(Tr, pam,  am);
        dm  = fmaf(Tr, pdm,  dm);
        Tr *= pTr;
    }

    if (grp == 0) {
        float* o5 = out + (size_t)ray * 5;
        o5[0] = active ? cm0 : 0.0f;
        o5[1] = active ? cm1 : 0.0f;
        o5[2] = active ? cm2 : 0.0f;
        o5[3] = active ? am  : 0.0f;
        o5[4] = active ? dm  : 0.0f;
    }
}

extern "C" void kernel_launch(void* const* d_in, const int* in_sizes, int n_in,
                              void* d_out, int out_size, void* d_ws, size_t ws_size,
                              hipStream_t stream) {
    const float* rays_o = (const float*)d_in[0];
    const float* rays_d = (const float*)d_in[1];
    const float* u      = (const float*)d_in[2];
    const float* aabb   = (const float*)d_in[3];
    const float* W1     = (const float*)d_in[4];
    const float* b1     = (const float*)d_in[5];
    const float* Wsigma = (const float*)d_in[6];
    const float* Wcolor = (const float*)d_in[7];
    const float* Wdir   = (const float*)d_in[8];
    float* out = (float*)d_out;

    int N = in_sizes[0] / 3;
    long long threads = (long long)N * 4;   // 4 lanes (segments) per ray
    int blocks = (int)((threads + 255) / 256);
    radiance_kernel<<<blocks, 256, 0, stream>>>(rays_o, rays_d, u, aabb,
                                                W1, b1, Wsigma, Wcolor, Wdir,
                                                out, N);
}

// Round 16
// 64.727 us; speedup vs baseline: 1.0483x; 1.0196x over previous
//
#include <hip/hip_runtime.h>

#define TS 64
#define HD 16
#define SEGLEN 16
#define RAY_EXT 10.0f

typedef float    v4f __attribute__((ext_vector_type(4)));
typedef _Float16 v8h __attribute__((ext_vector_type(8)));
typedef unsigned v4u __attribute__((ext_vector_type(4)));

__device__ __forceinline__ float fast_exp2(float x) { return __builtin_amdgcn_exp2f(x); }
__device__ __forceinline__ float fast_log2(float x) { return __builtin_amdgcn_logf(x); }

// pack two f32 into packed f16x2 (v_cvt_pkrtz_f16_f32)
__device__ __forceinline__ unsigned pack_f16x2(float a, float b) {
#if __has_builtin(__builtin_amdgcn_cvt_pkrtz)
    return __builtin_bit_cast(unsigned, __builtin_amdgcn_cvt_pkrtz(a, b));
#else
    unsigned r;
    asm("v_cvt_pkrtz_f16_f32 %0, %1, %2" : "=v"(r) : "v"(a), "v"(b));
    return r;
#endif
}

// fragment with k-slots 0..3 live, 4..7 zero
__device__ __forceinline__ v8h make_frag(unsigned lo, unsigned hi) {
    return __builtin_bit_cast(v8h, (v4u){lo, hi, 0u, 0u});
}

__device__ __forceinline__ v4f mfma32(v8h a, v8h b, v4f c) {
    return __builtin_amdgcn_mfma_f32_16x16x32_f16(a, b, c, 0, 0, 0);
}

__global__ __launch_bounds__(256) void radiance_kernel(
    const float* __restrict__ rays_o,
    const float* __restrict__ rays_d,
    const float* __restrict__ u,      // (T, N)
    const float* __restrict__ aabb,   // (2,3)
    const float* __restrict__ W1,     // (3,16)
    const float* __restrict__ b1,     // (16)
    const float* __restrict__ Wsigma, // (16,1)
    const float* __restrict__ Wcolor, // (16,3)
    const float* __restrict__ Wdir,   // (3,3)
    float* __restrict__ out,          // (N,5)
    int N)
{
    const float LOG2E = 1.44269504088896340736f;
    const float eps = 1e-9f;

    int tid  = blockIdx.x * blockDim.x + threadIdx.x;
    int lane = threadIdx.x & 63;
    int s    = lane & 15;     // ray-within-wave == MFMA column
    int grp  = lane >> 4;     // segment 0..3     == MFMA k/row block
    int wave = tid >> 6;
    int ray  = wave * 16 + s;

    float ox = rays_o[ray * 3 + 0];
    float oy = rays_o[ray * 3 + 1];
    float oz = rays_o[ray * 3 + 2];
    float dx = rays_d[ray * 3 + 0];
    float dy = rays_d[ray * 3 + 1];
    float dz = rays_d[ray * 3 + 2];

    float a0x = aabb[0], a0y = aabb[1], a0z = aabb[2];
    float a1x = aabb[3], a1y = aabb[4], a1z = aabb[5];

    // slab test (no early return: MFMA needs full waves)
    float dsx = (fabsf(dx) < eps) ? eps : dx;
    float dsy = (fabsf(dy) < eps) ? eps : dy;
    float dsz = (fabsf(dz) < eps) ? eps : dz;
    float t1x = (a0x - ox) / dsx, t2x = (a1x - ox) / dsx;
    float t1y = (a0y - oy) / dsy, t2y = (a1y - oy) / dsy;
    float t1z = (a0z - oz) / dsz, t2z = (a1z - oz) / dsz;
    float tnear = fmaxf(fmaxf(fminf(t1x, t2x), fmaxf(fminf(t1y, t2y), fminf(t1z, t2z))), 0.0f);
    float tfar  = fminf(fmaxf(t1x, t2x), fminf(fmaxf(t1y, t2y), fmaxf(t1z, t2z)));
    bool active = tnear < tfar;
    // sanitize inactive rays: pipeline stays finite, all weights w == 0.
    if (!active) { tnear = 0.0f; tfar = 0.0f; }

    // ---- A1 values (2 u32, lane-resident): A1[m=s][slot i] = {W1[0][s],W1[1][s],W1[2][s],b1[s]}
    unsigned w1lo = pack_f16x2(W1[0 * HD + s], W1[1 * HD + s]);
    unsigned w1hi = pack_f16x2(W1[2 * HD + s], b1[s]);

    // ---- A2 values: row m = s -> output o = s&3, owner pass = s>>2.
    //      A2[m=s][slot i] = W2eff[o][4*grp + i], pre-scaled into exp2 domain.
    int oidx = s & 3;
    int rgrp = s >> 2;
    float w2v0, w2v1, w2v2, w2v3;
    {
        int k0 = 4 * grp;
        if (oidx == 0) {
            w2v0 = LOG2E * Wsigma[k0 + 0]; w2v1 = LOG2E * Wsigma[k0 + 1];
            w2v2 = LOG2E * Wsigma[k0 + 2]; w2v3 = LOG2E * Wsigma[k0 + 3];
        } else {
            int c = oidx - 1;
            w2v0 = -LOG2E * Wcolor[(k0 + 0) * 3 + c];
            w2v1 = -LOG2E * Wcolor[(k0 + 1) * 3 + c];
            w2v2 = -LOG2E * Wcolor[(k0 + 2) * 3 + c];
            w2v3 = -LOG2E * Wcolor[(k0 + 3) * 3 + c];
        }
    }
    unsigned a2lo = pack_f16x2(w2v0, w2v1);
    unsigned a2hi = pack_f16x2(w2v2, w2v3);

    // direction encoding (pre-scaled by -log2e), per-ray
    float dn = sqrtf(dx * dx + dy * dy + dz * dz);
    float inv_dn = 1.0f / dn;
    float ux = dx * inv_dn, uy = dy * inv_dn, uz = dz * inv_dn;
    float dd0 = -LOG2E * (ux * Wdir[0] + uy * Wdir[3] + uz * Wdir[6]);
    float dd1 = -LOG2E * (ux * Wdir[1] + uy * Wdir[4] + uz * Wdir[7]);
    float dd2 = -LOG2E * (ux * Wdir[2] + uy * Wdir[5] + uz * Wdir[8]);

    const float invT = 1.0f / (float)TS;
    float rngT = (tfar - tnear) * invT;
    float tfinal = tfar * RAY_EXT;

    const int t0 = grp * SEGLEN;
    float t0f = (float)t0;

    // rolling u prefetch (2 ahead)
    float u_cur = u[(size_t)t0 * N + ray];
    float u_nxt = u[(size_t)(t0 + 1) * N + ray];

    float cm0 = 0.f, cm1 = 0.f, cm2 = 0.f, am = 0.f, dm = 0.f;
    float Tr = 1.0f;
    float ts = fmaf(rngT, t0f + u_cur, tnear);

#pragma unroll 4
    for (int t = 0; t < SEGLEN; ++t) {
        int gp = t0 + t + 2; gp = gp < TS - 1 ? gp : TS - 1;
        float u_fut = u[(size_t)gp * N + ray];        // used NEXT iteration

        float tf1 = t0f + (float)(t + 1);
        float tsn = fmaf(rngT, tf1 + u_nxt, tnear);
        float tend = (t == SEGLEN - 1) ? ((grp == 3) ? tfinal : tsn) : tsn;
        float delta = tend - ts;

        float x = fmaf(ts, dx, ox);
        float y = fmaf(ts, dy, oy);
        float z = fmaf(ts, dz, oz);
        // B1 (unconditional; per-pass selection lives on the A side)
        v8h bin = make_frag(pack_f16x2(x, y), pack_f16x2(z, 1.0f));

        v4f acc = {0.f, 0.f, 0.f, 0.f};
#pragma unroll
        for (int p = 0; p < 4; ++p) {
            bool own1 = (grp == p);
            v8h a1 = make_frag(own1 ? w1lo : 0u, own1 ? w1hi : 0u);
            // layer 1, pass p: only k-block p of A alive -> D1 = h of (ray s, segment p)
            v4f d1 = mfma32(a1, bin, (v4f){0.f, 0.f, 0.f, 0.f});
            // relu + repack: D1 row (l>>4)*4+r -> B2 slot r at lane group l>>4
            unsigned hlo = pack_f16x2(fmaxf(d1[0], 0.f), fmaxf(d1[1], 0.f));
            unsigned hhi = pack_f16x2(fmaxf(d1[2], 0.f), fmaxf(d1[3], 0.f));
            bool own2 = (rgrp == p);
            v8h a2 = make_frag(own2 ? a2lo : 0u, own2 ? a2hi : 0u);
            // layer 2, pass p: rows 4p..4p+3 of A2 alive -> lands on group-p lanes' regs
            acc = mfma32(a2, make_frag(hlo, hhi), acc);
        }

        // acc[0] = sigma-logit*log2e ; acc[1..3] = -color-logit*log2e (sans dir term)
        float sp = acc[0];
        float c0 = acc[1] + dd0;
        float c1 = acc[2] + dd1;
        float c2 = acc[3] + dd2;

        float F = fmaxf(sp, 0.0f) + fast_log2(1.0f + fast_exp2(-fabsf(sp)));
        float e = fast_exp2(-F * (delta * dn));

        float col0 = __builtin_amdgcn_rcpf(1.0f + fast_exp2(c0));
        float col1 = __builtin_amdgcn_rcpf(1.0f + fast_exp2(c1));
        float col2 = __builtin_amdgcn_rcpf(1.0f + fast_exp2(c2));

        float w = (1.0f - e) * Tr;
        Tr *= e;

        cm0 = fmaf(w, col0, cm0);
        cm1 = fmaf(w, col1, cm1);
        cm2 = fmaf(w, col2, cm2);
        am += w;
        dm = fmaf(w, ts, dm);

        ts = tsn;
        u_nxt = u_fut;
    }

    // ---- combine 4 segments across lane groups: butterfly xor 16, then 32.
    // Earlier-segment lanes compute ordered results; later lanes' junk never read.
#pragma unroll
    for (int x = 16; x <= 32; x <<= 1) {
        float pcm0 = __shfl_xor(cm0, x, 64);
        float pcm1 = __shfl_xor(cm1, x, 64);
        float pcm2 = __shfl_xor(cm2, x, 64);
        float pam  = __shfl_xor(am, x, 64);
        float pdm  = __shfl_xor(dm, x, 64);
        float pTr  = __shfl_xor(Tr, x, 64);
        cm0 = fmaf(Tr, pcm0, cm0);
        cm1 = fmaf(Tr, pcm1, cm1);
        cm2 = fmaf(Tr, pcm2, cm2);
        am  = fmaf(Tr, pam,  am);
        dm  = fmaf(Tr, pdm,  dm);
        Tr *= pTr;
    }

    if (grp == 0) {
        float* o5 = out + (size_t)ray * 5;
        o5[0] = active ? cm0 : 0.0f;
        o5[1] = active ? cm1 : 0.0f;
        o5[2] = active ? cm2 : 0.0f;
        o5[3] = active ? am  : 0.0f;
        o5[4] = active ? dm  : 0.0f;
    }
}

extern "C" void kernel_launch(void* const* d_in, const int* in_sizes, int n_in,
                              void* d_out, int out_size, void* d_ws, size_t ws_size,
                              hipStream_t stream) {
    const float* rays_o = (const float*)d_in[0];
    const float* rays_d = (const float*)d_in[1];
    const float* u      = (const float*)d_in[2];
    const float* aabb   = (const float*)d_in[3];
    const float* W1     = (const float*)d_in[4];
    const float* b1     = (const float*)d_in[5];
    const float* Wsigma = (const float*)d_in[6];
    const float* Wcolor = (const float*)d_in[7];
    const float* Wdir   = (const float*)d_in[8];
    float* out = (float*)d_out;

    int N = in_sizes[0] / 3;
    long long threads = (long long)N * 4;   // 4 lanes (segments) per ray
    int blocks = (int)((threads + 255) / 256);
    radiance_kernel<<<blocks, 256, 0, stream>>>(rays_o, rays_d, u, aabb,
                                                W1, b1, Wsigma, Wcolor, Wdir,
                                                out, N);
}